// Round 8
// baseline (556.927 us; speedup 1.0000x reference)
//
#include <hip/hip_runtime.h>
#include <math.h>

// ---- problem constants (from reference) ----
constexpr int B_  = 4;
constexpr int S_  = 4096;
constexpr int D_  = 1024;   // DIM
constexpr int IN_ = 2048;   // INNER
constexpr float EPS_ = 1e-8f;
constexpr int NCH_ = 128;         // chunks per sequence for the scan
constexpr int CS_  = S_ / NCH_;   // 32 timesteps per chunk
constexpr float LOG2E_ = 1.4426950408889634f;
constexpr float LN2_   = 0.6931471805599453f;

typedef __attribute__((ext_vector_type(8))) _Float16 f16x8;
typedef __attribute__((ext_vector_type(2))) _Float16 h2;
typedef __attribute__((ext_vector_type(4))) float    f32x4;

#define BAR() asm volatile("s_barrier" ::: "memory")

// ---- helpers ----
__device__ __forceinline__ h2 pkrtz(float a, float b) {
  auto r = __builtin_amdgcn_cvt_pkrtz(a, b);
  union { decltype(r) r_; h2 h; } c; c.r_ = r; return c.h;
}
__device__ __forceinline__ unsigned packh2(float a, float b) {
  auto r = __builtin_amdgcn_cvt_pkrtz(a, b);
  union { decltype(r) r_; unsigned u; } c; c.r_ = r; return c.u;
}
__device__ __forceinline__ void unpack_h8(uint4 v, float* f) {
  union { uint4 u; _Float16 h[8]; } c; c.u = v;
  #pragma unroll
  for (int i = 0; i < 8; ++i) f[i] = (float)c.h[i];
}
__device__ __forceinline__ float spf_fast(float t) {       // softplus log(1+e^t)
  const float e = __builtin_amdgcn_exp2f(-fabsf(t) * LOG2E_);
  return fmaxf(t, 0.0f) + LN2_ * __builtin_amdgcn_logf(1.0f + e);
}
__device__ __forceinline__ float siluf(float x) {
  return x * __builtin_amdgcn_rcpf(1.0f + __builtin_amdgcn_exp2f(-x * LOG2E_));
}

// async global->LDS, 16 B per lane (wave-uniform LDS base + lane*16)
__device__ __forceinline__ void gload16(const void* g, void* l) {
  __builtin_amdgcn_global_load_lds(
      (const __attribute__((address_space(1))) void*)g,
      (__attribute__((address_space(3))) void*)l,
      16, 0, 0);
}

// ---------------------------------------------------------------------------
// fp32 -> f16 conversion (8 elems/thread)
// ---------------------------------------------------------------------------
__launch_bounds__(256)
__global__ void cvt_f16(const float* __restrict__ in, unsigned* __restrict__ outp,
                        long n8)
{
  const long stride = (long)gridDim.x * blockDim.x;
  for (long i = (long)blockIdx.x * blockDim.x + threadIdx.x; i < n8; i += stride) {
    const float4 a = *(const float4*)(in + i * 8);
    const float4 b = *(const float4*)(in + i * 8 + 4);
    uint4 o;
    o.x = packh2(a.x, a.y);
    o.y = packh2(a.z, a.w);
    o.z = packh2(b.x, b.y);
    o.w = packh2(b.z, b.w);
    *(uint4*)(outp + i * 4) = o;
  }
}

// ---------------------------------------------------------------------------
// f16 MFMA NT GEMM, 4-phase schedule, 256x256 tile, BK=64, 8 waves (2Mx4N),
// double-buffered LDS (128 KiB), XOR-16B-block swizzle, counted vmcnt,
// setprio around MFMA clusters, bijective XCD-aware block swizzle.
// MODE 0: A = f16 matrix; split epilogue -> xmin(f16) | silu(z)(f16) via
//         per-wave LDS transpose (16B full-line stores).
// MODE 1: A = f16 matrix; fp32 out, direct stores.
// MODE 2: A built on the fly: G = (hlast + skip*act)*silu(z), reg-staged
//         (loads issued phase 0, G-compute + swizzled ds_write in phase 3);
//         fp32 out. Replaces the standalone gfuse kernel.
// ---------------------------------------------------------------------------
template<int MODE>
__launch_bounds__(512, 2)
__global__ void gemm_mfma(const unsigned short* __restrict__ Ab,
                          const unsigned short* __restrict__ Bb,
                          const float* __restrict__ bias,
                          void* __restrict__ out0,
                          unsigned short* __restrict__ out1,
                          int M, int N, int K,
                          const unsigned short* __restrict__ Zsb,
                          const float* __restrict__ hlast,
                          const float* __restrict__ skipv)
{
  constexpr int BM = 256, BN = 256, BK = 64;
  __shared__ __align__(16) unsigned short As[2][BM * BK];  // 2 x 32 KB
  __shared__ __align__(16) unsigned short Bs[2][BN * BK];  // 2 x 32 KB

  const int tid  = threadIdx.x;
  const int lane = tid & 63;
  const int w    = tid >> 6;       // 0..7
  const int wm   = w >> 2;         // 0..1  (M half)
  const int wn   = w & 3;          // 0..3  (N quarter)

  // bijective XCD swizzle: each XCD gets a contiguous chunk of tiles
  const int GX  = gridDim.x;
  const int nwg = GX * gridDim.y;           // divisible by 8 for our shapes
  int lin = blockIdx.y * GX + blockIdx.x;
  lin = (lin & 7) * (nwg >> 3) + (lin >> 3);
  const int m0 = (lin / GX) * BM;
  const int n0 = (lin % GX) * BN;
  const int NT = K / BK;

  // staging geometry: one call = 64 rows; wave w covers rows c*64+w*8 .. +7
  const int sr   = lane >> 3;                   // 0..7 row-in-slice
  const int sblk = ((lane & 7) ^ sr) * 8;       // pre-swizzled global col (elems)
  const int lblk = (lane & 7) * 8;              // linear LDS col (reg-staged path)

  // fragment read geometry: row&7 == lane&7 for all fragment rows
  const int fr  = lane & 15;
  const int fb0 = (((lane >> 4) + 0) ^ (lane & 7)) * 8;   // k-step 0
  const int fb1 = (((lane >> 4) + 4) ^ (lane & 7)) * 8;   // k-step 1

  const float* hlp = (MODE == 2) ? (hlast + (size_t)(m0 >> 12) * IN_) : nullptr;

  auto stage64 = [&](const unsigned short* Gp, int Kd, int grow0, int kOff,
                     unsigned short* lchunk) {
    gload16(Gp + (size_t)(grow0 + w * 8 + sr) * Kd + kOff + sblk,
            lchunk + (w * 8) * BK);
  };

  // G-compute for MODE 2: per-chunk, from reg-staged act/z + hl/sk vectors
  auto gcompute = [&](uint4 rau, uint4 rzu, const float* hv, const float* sv,
                      unsigned short* dstp, int c) {
    float a[8], z[8];
    unpack_h8(rau, a); unpack_h8(rzu, z);
    uint4 gw;
    gw.x = packh2((hv[0] + sv[0] * a[0]) * z[0], (hv[1] + sv[1] * a[1]) * z[1]);
    gw.y = packh2((hv[2] + sv[2] * a[2]) * z[2], (hv[3] + sv[3] * a[3]) * z[3]);
    gw.z = packh2((hv[4] + sv[4] * a[4]) * z[4], (hv[5] + sv[5] * a[5]) * z[5]);
    gw.w = packh2((hv[6] + sv[6] * a[6]) * z[6], (hv[7] + sv[7] * a[7]) * z[7]);
    *(uint4*)&dstp[(c * 64 + w * 8 + sr) * BK + lblk] = gw;
  };

  f32x4 acc[8][4] = {};

  // ---- prologue: stage tiles 0 and 1 ----
  if (MODE == 2) {
    uint4 pa[2][4], pz[2][4];
    float4 phl[2][2], psk[2][2];
    #pragma unroll
    for (int tt = 0; tt < 2; ++tt) {
      const int kO = tt * BK;
      #pragma unroll
      for (int c = 0; c < 4; ++c) {
        const size_t gr = (size_t)(m0 + c * 64 + w * 8 + sr) * K + kO + sblk;
        pa[tt][c] = *(const uint4*)(Ab + gr);
        pz[tt][c] = *(const uint4*)(Zsb + gr);
      }
      phl[tt][0] = *(const float4*)(hlp + kO + sblk);
      phl[tt][1] = *(const float4*)(hlp + kO + sblk + 4);
      psk[tt][0] = *(const float4*)(skipv + kO + sblk);
      psk[tt][1] = *(const float4*)(skipv + kO + sblk + 4);
    }
    #pragma unroll
    for (int c = 0; c < 4; ++c) stage64(Bb, K, n0 + c * 64, 0,  &Bs[0][c * 64 * BK]);
    #pragma unroll
    for (int c = 0; c < 4; ++c) stage64(Bb, K, n0 + c * 64, BK, &Bs[1][c * 64 * BK]);
    #pragma unroll
    for (int tt = 0; tt < 2; ++tt) {
      float hv[8], sv[8];
      *(float4*)hv = phl[tt][0]; *(float4*)(hv + 4) = phl[tt][1];
      *(float4*)sv = psk[tt][0]; *(float4*)(sv + 4) = psk[tt][1];
      #pragma unroll
      for (int c = 0; c < 4; ++c)
        gcompute(pa[tt][c], pz[tt][c], hv, sv,
                 tt ? (unsigned short*)As[1] : (unsigned short*)As[0], c);
    }
    asm volatile("s_waitcnt lgkmcnt(0)" ::: "memory");
    asm volatile("s_waitcnt vmcnt(4)" ::: "memory");   // B tile 0 landed
  } else {
    #pragma unroll
    for (int c = 0; c < 4; ++c) stage64(Ab, K, m0 + c * 64, 0, &As[0][c * 64 * BK]);
    #pragma unroll
    for (int c = 0; c < 4; ++c) stage64(Bb, K, n0 + c * 64, 0, &Bs[0][c * 64 * BK]);
    #pragma unroll
    for (int c = 0; c < 4; ++c) stage64(Ab, K, m0 + c * 64, BK, &As[1][c * 64 * BK]);
    #pragma unroll
    for (int c = 0; c < 4; ++c) stage64(Bb, K, n0 + c * 64, BK, &Bs[1][c * 64 * BK]);
    asm volatile("s_waitcnt vmcnt(8)" ::: "memory");   // tile 0 landed
  }
  BAR();

  for (int t = 0; t < NT; ++t) {
    const int cur = t & 1;
    const unsigned short* AL = As[cur];
    const unsigned short* BL = Bs[cur];
    const int  nxtK = (t + 2) * BK;
    const bool more = (t + 2 < NT);

    f16x8 af[4][2], bf[4][2];

    // MODE 2: issue next-next A reg-loads early (3 phases of latency hiding;
    // the "memory"-clobbered barriers pin them in this region)
    uint4 ra[4], rz[4]; float4 rh[2], rs[2];
    if (MODE == 2 && more) {
      #pragma unroll
      for (int c = 0; c < 4; ++c) {
        const size_t gr = (size_t)(m0 + c * 64 + w * 8 + sr) * K + nxtK + sblk;
        ra[c] = *(const uint4*)(Ab + gr);
        rz[c] = *(const uint4*)(Zsb + gr);
      }
      rh[0] = *(const float4*)(hlp + nxtK + sblk);
      rh[1] = *(const float4*)(hlp + nxtK + sblk + 4);
      rs[0] = *(const float4*)(skipv + nxtK + sblk);
      rs[1] = *(const float4*)(skipv + nxtK + sblk + 4);
    }

    // ---- phase 0: quadrant (mq=0, nq=0)
    #pragma unroll
    for (int i = 0; i < 4; ++i) {
      const int row = wm * 128 + i * 16 + fr;
      af[i][0] = *(const f16x8*)&AL[row * BK + fb0];
      af[i][1] = *(const f16x8*)&AL[row * BK + fb1];
    }
    #pragma unroll
    for (int j = 0; j < 2; ++j) {
      const int row = wn * 64 + j * 16 + fr;
      bf[j][0] = *(const f16x8*)&BL[row * BK + fb0];
      bf[j][1] = *(const f16x8*)&BL[row * BK + fb1];
    }
    BAR();
    __builtin_amdgcn_s_setprio(1);
    #pragma unroll
    for (int i = 0; i < 4; ++i)
      #pragma unroll
      for (int j = 0; j < 2; ++j) {
        acc[i][j] = __builtin_amdgcn_mfma_f32_16x16x32_f16(af[i][0], bf[j][0], acc[i][j], 0, 0, 0);
        acc[i][j] = __builtin_amdgcn_mfma_f32_16x16x32_f16(af[i][1], bf[j][1], acc[i][j], 0, 0, 0);
      }
    __builtin_amdgcn_s_setprio(0);
    BAR();

    // ---- phase 1: (mq=0, nq=1)
    #pragma unroll
    for (int j = 2; j < 4; ++j) {
      const int row = wn * 64 + j * 16 + fr;
      bf[j][0] = *(const f16x8*)&BL[row * BK + fb0];
      bf[j][1] = *(const f16x8*)&BL[row * BK + fb1];
    }
    BAR();
    __builtin_amdgcn_s_setprio(1);
    #pragma unroll
    for (int i = 0; i < 4; ++i)
      #pragma unroll
      for (int j = 2; j < 4; ++j) {
        acc[i][j] = __builtin_amdgcn_mfma_f32_16x16x32_f16(af[i][0], bf[j][0], acc[i][j], 0, 0, 0);
        acc[i][j] = __builtin_amdgcn_mfma_f32_16x16x32_f16(af[i][1], bf[j][1], acc[i][j], 0, 0, 0);
      }
    __builtin_amdgcn_s_setprio(0);
    BAR();

    // ---- phase 2: (mq=1, nq=0) ; stage B rows 0-127 of t+2
    #pragma unroll
    for (int i = 0; i < 4; ++i) {
      const int row = wm * 128 + 64 + i * 16 + fr;
      af[i][0] = *(const f16x8*)&AL[row * BK + fb0];
      af[i][1] = *(const f16x8*)&AL[row * BK + fb1];
    }
    if (more) {
      stage64(Bb, K, n0 +  0, nxtK, &Bs[cur][0]);
      stage64(Bb, K, n0 + 64, nxtK, &Bs[cur][64 * BK]);
    }
    BAR();
    __builtin_amdgcn_s_setprio(1);
    #pragma unroll
    for (int i = 0; i < 4; ++i)
      #pragma unroll
      for (int j = 0; j < 2; ++j) {
        acc[4 + i][j] = __builtin_amdgcn_mfma_f32_16x16x32_f16(af[i][0], bf[j][0], acc[4 + i][j], 0, 0, 0);
        acc[4 + i][j] = __builtin_amdgcn_mfma_f32_16x16x32_f16(af[i][1], bf[j][1], acc[4 + i][j], 0, 0, 0);
      }
    __builtin_amdgcn_s_setprio(0);
    BAR();

    // ---- phase 3: (mq=1, nq=1) ; stage B rows 128-255 + A of t+2
    if (more) {
      stage64(Bb, K, n0 + 128, nxtK, &Bs[cur][128 * BK]);
      stage64(Bb, K, n0 + 192, nxtK, &Bs[cur][192 * BK]);
      if (MODE == 2) {
        // compiler inserts the vmcnt wait for ra/rz/rh/rs here; that wait
        // also guarantees tile t+1's B (issued one iter earlier) has landed
        float hv[8], sv[8];
        *(float4*)hv = rh[0]; *(float4*)(hv + 4) = rh[1];
        *(float4*)sv = rs[0]; *(float4*)(sv + 4) = rs[1];
        #pragma unroll
        for (int c = 0; c < 4; ++c)
          gcompute(ra[c], rz[c], hv, sv, (unsigned short*)As[cur], c);
        asm volatile("s_waitcnt lgkmcnt(0)" ::: "memory");
      } else {
        #pragma unroll
        for (int c = 0; c < 4; ++c)
          stage64(Ab, K, m0 + c * 64, nxtK, &As[cur][c * 64 * BK]);
      }
    }
    BAR();
    __builtin_amdgcn_s_setprio(1);
    #pragma unroll
    for (int i = 0; i < 4; ++i)
      #pragma unroll
      for (int j = 2; j < 4; ++j) {
        acc[4 + i][j] = __builtin_amdgcn_mfma_f32_16x16x32_f16(af[i][0], bf[j][0], acc[4 + i][j], 0, 0, 0);
        acc[4 + i][j] = __builtin_amdgcn_mfma_f32_16x16x32_f16(af[i][1], bf[j][1], acc[4 + i][j], 0, 0, 0);
      }
    __builtin_amdgcn_s_setprio(0);
    if (MODE == 2) {
      if (!more) asm volatile("s_waitcnt vmcnt(0)" ::: "memory");
    } else {
      if (more) asm volatile("s_waitcnt vmcnt(8)" ::: "memory");
      else      asm volatile("s_waitcnt vmcnt(0)" ::: "memory");
    }
    BAR();
  }

  // ---- epilogue ----
  const int col = lane & 15;
  const int rb4 = (lane >> 4) * 4;

  if (MODE != 0) {
    // fp32 direct stores: lanes 0-15 cover 64B contiguous per row
    #pragma unroll
    for (int j = 0; j < 4; ++j) {
      const int n  = n0 + wn * 64 + j * 16 + col;
      const float bv = bias[n];
      #pragma unroll
      for (int i = 0; i < 8; ++i) {
        const int mb = m0 + wm * 128 + i * 16 + rb4;
        #pragma unroll
        for (int r = 0; r < 4; ++r)
          ((float*)out0)[(size_t)(mb + r) * N + n] = acc[i][j][r] + bv;
      }
    }
  } else {
    // f16 split outputs via per-wave LDS transpose -> 16B full-line stores.
    constexpr int RS = 72;
    unsigned short* eb = (w < 4) ? ((unsigned short*)As + w * (64 * RS))
                                 : ((unsigned short*)Bs + (w - 4) * (64 * RS));
    const bool zhalf = (n0 >= IN_);   // block-uniform: n-tiles don't straddle
    float bv[4];
    #pragma unroll
    for (int j = 0; j < 4; ++j) bv[j] = bias[n0 + wn * 64 + j * 16 + col];

    const int lrow = lane >> 3;
    const int lc8  = (lane & 7) * 8;
    unsigned short* dst = zhalf ? out1 : (unsigned short*)out0;
    const int ncol0 = (zhalf ? n0 - IN_ : n0) + wn * 64 + lc8;

    #pragma unroll
    for (int h = 0; h < 2; ++h) {
      asm volatile("s_waitcnt lgkmcnt(0)" ::: "memory");  // slice reusable
      #pragma unroll
      for (int i2 = 0; i2 < 4; ++i2)
        #pragma unroll
        for (int j = 0; j < 4; ++j)
          #pragma unroll
          for (int r = 0; r < 4; ++r) {
            const float v = acc[h * 4 + i2][j][r] + bv[j];
            ((_Float16*)eb)[(i2 * 16 + rb4 + r) * RS + j * 16 + col] = (_Float16)v;
          }
      asm volatile("s_waitcnt lgkmcnt(0)" ::: "memory");
      #pragma unroll
      for (int it = 0; it < 8; ++it) {
        const int row = it * 8 + lrow;
        uint4 d = *(const uint4*)&eb[row * RS + lc8];
        if (zhalf) {
          float f[8];
          unpack_h8(d, f);
          d.x = packh2(siluf(f[0]), siluf(f[1]));
          d.y = packh2(siluf(f[2]), siluf(f[3]));
          d.z = packh2(siluf(f[4]), siluf(f[5]));
          d.w = packh2(siluf(f[6]), siluf(f[7]));
        }
        const int m = m0 + wm * 128 + h * 64 + row;
        *(uint4*)(dst + (size_t)m * IN_ + ncol0) = d;
      }
    }
  }
}

// ---------------------------------------------------------------------------
// causal depthwise conv (K=4, left pad 3) + SiLU.  f16 in/out, 8 ch/thread.
// ---------------------------------------------------------------------------
__launch_bounds__(256)
__global__ void conv_silu_k(const unsigned* __restrict__ xm,
                            const float* __restrict__ cw,   // (IN_,1,4)
                            const float* __restrict__ cb,
                            unsigned* __restrict__ act)
{
  const size_t total  = (size_t)B_ * S_ * IN_ / 8;
  const size_t stride = (size_t)gridDim.x * blockDim.x;
  for (size_t t = (size_t)blockIdx.x * blockDim.x + threadIdx.x; t < total; t += stride) {
    const size_t e = t * 8;
    const int    c  = (int)(e % IN_);
    const size_t bs = e / IN_;          // b*S_ + s
    const int    s  = (int)(bs % S_);
    float w[8][4];
    #pragma unroll
    for (int j = 0; j < 8; ++j)
      *(float4*)w[j] = *(const float4*)(cw + (size_t)(c + j) * 4);
    float r[8];
    *(float4*)(r)     = *(const float4*)(cb + c);
    *(float4*)(r + 4) = *(const float4*)(cb + c + 4);
    #pragma unroll
    for (int k = 0; k < 4; ++k) {
      const int ss = s - 3 + k;
      if (ss >= 0) {
        const uint4 xv = *(const uint4*)(xm + ((size_t)bs + k - 3) * (IN_ / 2) + c / 2);
        float xf[8];
        unpack_h8(xv, xf);
        #pragma unroll
        for (int j = 0; j < 8; ++j) r[j] = fmaf(xf[j], w[j][k], r[j]);
      }
    }
    uint4 o;
    o.x = packh2(siluf(r[0]), siluf(r[1]));
    o.y = packh2(siluf(r[2]), siluf(r[3]));
    o.z = packh2(siluf(r[4]), siluf(r[5]));
    o.w = packh2(siluf(r[6]), siluf(r[7]));
    *(uint4*)(act + e / 2) = o;
  }
}

// ---------------------------------------------------------------------------
// grouped 16x16 gate projections + per-chunk scan partials.
// ---------------------------------------------------------------------------
__launch_bounds__(256)
__global__ void gates_scan(const unsigned* __restrict__ actb,
                           const float* __restrict__ wf,
                           const float* __restrict__ wi,
                           const float* __restrict__ wh,
                           float2* __restrict__ part)   // [B_*IN_][NCH_]
{
  const int T  = blockIdx.x * 256 + threadIdx.x;
  const int o  = T & 15;
  const int g  = (T >> 4) & 127;
  const int ck = (T >> 11) & (NCH_ - 1);
  const int b  = T >> 18;

  h2 Wf2[8], Wi2[8], Wh2[8];
  const float* pf = wf + ((size_t)g * 16 + o) * 16;
  const float* pi = wi + ((size_t)g * 16 + o) * 16;
  const float* ph = wh + ((size_t)g * 16 + o) * 16;
  #pragma unroll
  for (int i = 0; i < 8; ++i) {
    Wf2[i] = pkrtz(pf[2 * i], pf[2 * i + 1]);
    Wi2[i] = pkrtz(pi[2 * i], pi[2 * i + 1]);
    Wh2[i] = pkrtz(ph[2 * i], ph[2 * i + 1]);
  }

  float p = 0.0f, Mx = -INFINITY, Ss = 0.0f;
  const unsigned* ap = actb + ((size_t)b * S_ + (size_t)ck * CS_) * (IN_ / 2) + g * 8;
  for (int s = 0; s < CS_; ++s) {
    union { uint4 u; h2 h[4]; } A0, A1;
    A0.u = *(const uint4*)(ap);
    A1.u = *(const uint4*)(ap + 4);
    ap += IN_ / 2;
    float fg = 0.0f, ig = 0.0f, hd = 0.0f;
    #pragma unroll
    for (int i = 0; i < 4; ++i) {
      fg = __builtin_amdgcn_fdot2(A0.h[i], Wf2[i], fg, false);
      ig = __builtin_amdgcn_fdot2(A0.h[i], Wi2[i], ig, false);
      hd = __builtin_amdgcn_fdot2(A0.h[i], Wh2[i], hd, false);
    }
    #pragma unroll
    for (int i = 0; i < 4; ++i) {
      fg = __builtin_amdgcn_fdot2(A1.h[i], Wf2[i + 4], fg, false);
      ig = __builtin_amdgcn_fdot2(A1.h[i], Wi2[i + 4], ig, false);
      hd = __builtin_amdgcn_fdot2(A1.h[i], Wh2[i + 4], hd, false);
    }
    const float diff  = spf_fast(-fg) - spf_fast(-ig);
    const float log_f = -spf_fast(diff);
    const float log_i = diff + log_f;          // sp(-d) = sp(d) - d
    const float lpos  = LN2_ * __builtin_amdgcn_logf(hd + 0.5f + EPS_);
    const float lneg  = -spf_fast(-hd) + EPS_;
    const float log_th = (hd >= 0.0f) ? lpos : lneg;
    p += log_f + EPS_;
    const float v = log_i + log_th - p;
    const float m = fmaxf(Mx, v);
    Ss = Ss * __builtin_amdgcn_exp2f((Mx - m) * LOG2E_)
       + __builtin_amdgcn_exp2f((v - m) * LOG2E_);
    Mx = m;
  }
  part[((size_t)(b * IN_ + g * 16 + o)) * NCH_ + ck] =
      make_float2(p, Mx + LN2_ * __builtin_amdgcn_logf(Ss));
}

// ---------------------------------------------------------------------------
// combine chunk partials -> h_last[b, c]
// ---------------------------------------------------------------------------
__launch_bounds__(256)
__global__ void combine_k(const float2* __restrict__ part, float* __restrict__ hlast)
{
  const int seq = blockIdx.x * 256 + threadIdx.x;
  if (seq >= B_ * IN_) return;
  const float2* pp = part + (size_t)seq * NCH_;
  float P = 0.0f, Mx = -INFINITY, Ss = 0.0f;
  for (int c = 0; c < NCH_; ++c) {
    const float2 al = pp[c];
    const float v = al.y - P;
    const float m = fmaxf(Mx, v);
    Ss = Ss * __builtin_amdgcn_exp2f((Mx - m) * LOG2E_)
       + __builtin_amdgcn_exp2f((v - m) * LOG2E_);
    Mx = m;
    P += al.x;
  }
  hlast[seq] = __builtin_amdgcn_exp2f((P + Mx) * LOG2E_) * Ss;
}

// ---------------------------------------------------------------------------
extern "C" void kernel_launch(void* const* d_in, const int* in_sizes, int n_in,
                              void* d_out, int out_size, void* d_ws, size_t ws_size,
                              hipStream_t stream)
{
  const float* x     = (const float*)d_in[0];
  const float* w_up  = (const float*)d_in[1];
  const float* b_up  = (const float*)d_in[2];
  const float* cw    = (const float*)d_in[3];
  const float* cb    = (const float*)d_in[4];
  const float* skipv = (const float*)d_in[5];
  const float* w_f   = (const float*)d_in[6];
  const float* w_i   = (const float*)d_in[7];
  const float* w_h   = (const float*)d_in[8];
  const float* w_dn  = (const float*)d_in[9];
  const float* b_dn  = (const float*)d_in[10];
  float* out = (float*)d_out;

  // workspace layout with lifetime-based aliasing (max ~210 MB):
  //  [0,   67M): xminb (dead after conv) -> then wdb @0 (4MB),
  //              part @8.39M (8.39MB), hlast @16.78M (32KB)
  //  [67M, 134M): zb (silu(z), stays pristine; G fused into gemm-down)
  //  [134M,201M): actb;  xb (f16 x, 33.5M) aliases this region (dead pre-conv)
  //  [201M,210M): wub (8.4MB)
  char* ws = (char*)d_ws;
  unsigned short* xminb = (unsigned short*)(ws);
  unsigned short* wdb   = (unsigned short*)(ws);                    // after conv
  float2*         part  = (float2*)(ws + 8388608ULL);               // after conv
  float*          hlast = (float*)(ws + 16777216ULL);               // after conv
  unsigned short* zb    = (unsigned short*)(ws + 67108864ULL);
  unsigned short* actb  = (unsigned short*)(ws + 134217728ULL);
  unsigned short* xb    = (unsigned short*)(ws + 134217728ULL);     // pre-conv alias
  unsigned short* wub   = (unsigned short*)(ws + 201326592ULL);

  const int M = B_ * S_;   // 16384

  // 0) fp32 -> f16 conversions for MFMA operands
  cvt_f16<<<2048, 256, 0, stream>>>(x,    (unsigned*)xb,  (long)M * D_ / 8);
  cvt_f16<<<512,  256, 0, stream>>>(w_up, (unsigned*)wub, (long)2 * IN_ * D_ / 8);

  // 1) proj-up: xb @ wub^T + b_up -> xmin(f16) | silu(z)(f16)
  gemm_mfma<0><<<dim3((2 * IN_) / 256, M / 256), 512, 0, stream>>>(
      xb, wub, b_up, xminb, (unsigned short*)zb, M, 2 * IN_, D_,
      nullptr, nullptr, nullptr);

  // 2) causal depthwise conv + SiLU -> act(f16)
  conv_silu_k<<<2048, 256, 0, stream>>>((const unsigned*)xminb, cw, cb, (unsigned*)actb);

  // 2b) w_down -> f16 (into region freed by xminb)
  cvt_f16<<<256, 256, 0, stream>>>(w_dn, (unsigned*)wdb, (long)D_ * IN_ / 8);

  // 3) grouped gate projections + chunked scan partials
  gates_scan<<<(B_ * 128 * 16 * NCH_) / 256, 256, 0, stream>>>(
      (const unsigned*)actb, w_f, w_i, w_h, part);

  // 4) combine partials -> h_last
  combine_k<<<(B_ * IN_ + 255) / 256, 256, 0, stream>>>(part, hlast);

  // 5+6) proj-down with fused G = (hlast + skip*act)*silu(z) A-construction
  gemm_mfma<2><<<dim3(D_ / 256, M / 256), 512, 0, stream>>>(
      actb, wdb, b_dn, out, nullptr, M, D_, IN_,
      zb, hlast, skipv);
}

// Round 9
// 409.642 us; speedup vs baseline: 1.3595x; 1.3595x over previous
//
#include <hip/hip_runtime.h>
#include <math.h>

// ---- problem constants (from reference) ----
constexpr int B_  = 4;
constexpr int S_  = 4096;
constexpr int D_  = 1024;   // DIM
constexpr int IN_ = 2048;   // INNER
constexpr float EPS_ = 1e-8f;
constexpr int NCH_ = 128;         // chunks per sequence for the scan
constexpr int CS_  = S_ / NCH_;   // 32 timesteps per chunk
constexpr float LOG2E_ = 1.4426950408889634f;
constexpr float LN2_   = 0.6931471805599453f;

typedef __attribute__((ext_vector_type(8))) _Float16 f16x8;
typedef __attribute__((ext_vector_type(2))) _Float16 h2;
typedef __attribute__((ext_vector_type(4))) float    f32x4;

#define BAR() asm volatile("s_barrier" ::: "memory")

// ---- helpers ----
__device__ __forceinline__ h2 pkrtz(float a, float b) {
  auto r = __builtin_amdgcn_cvt_pkrtz(a, b);
  union { decltype(r) r_; h2 h; } c; c.r_ = r; return c.h;
}
__device__ __forceinline__ unsigned packh2(float a, float b) {
  auto r = __builtin_amdgcn_cvt_pkrtz(a, b);
  union { decltype(r) r_; unsigned u; } c; c.r_ = r; return c.u;
}
__device__ __forceinline__ void unpack_h8(uint4 v, float* f) {
  union { uint4 u; _Float16 h[8]; } c; c.u = v;
  #pragma unroll
  for (int i = 0; i < 8; ++i) f[i] = (float)c.h[i];
}
__device__ __forceinline__ float spf_fast(float t) {       // softplus log(1+e^t)
  const float e = __builtin_amdgcn_exp2f(-fabsf(t) * LOG2E_);
  return fmaxf(t, 0.0f) + LN2_ * __builtin_amdgcn_logf(1.0f + e);
}
__device__ __forceinline__ float siluf(float x) {
  return x * __builtin_amdgcn_rcpf(1.0f + __builtin_amdgcn_exp2f(-x * LOG2E_));
}

// async global->LDS, 16 B per lane (wave-uniform LDS base + lane*16)
__device__ __forceinline__ void gload16(const void* g, void* l) {
  __builtin_amdgcn_global_load_lds(
      (const __attribute__((address_space(1))) void*)g,
      (__attribute__((address_space(3))) void*)l,
      16, 0, 0);
}

// ---------------------------------------------------------------------------
// fp32 -> f16 conversion (8 elems/thread)
// ---------------------------------------------------------------------------
__launch_bounds__(256)
__global__ void cvt_f16(const float* __restrict__ in, unsigned* __restrict__ outp,
                        long n8)
{
  const long stride = (long)gridDim.x * blockDim.x;
  for (long i = (long)blockIdx.x * blockDim.x + threadIdx.x; i < n8; i += stride) {
    const float4 a = *(const float4*)(in + i * 8);
    const float4 b = *(const float4*)(in + i * 8 + 4);
    uint4 o;
    o.x = packh2(a.x, a.y);
    o.y = packh2(a.z, a.w);
    o.z = packh2(b.x, b.y);
    o.w = packh2(b.z, b.w);
    *(uint4*)(outp + i * 4) = o;
  }
}

// ---------------------------------------------------------------------------
// f16 MFMA NT GEMM, 4-phase schedule, 256x256 tile, BK=64, 8 waves (2Mx4N),
// double-buffered LDS (128 KiB), XOR-16B-block swizzle, counted vmcnt(8),
// setprio around MFMA clusters, bijective XCD-aware block swizzle,
// staging spread 4+4 across phases 2/3.
// MODE 0: split epilogue -> xmin(f16) | silu(z)(f16) via per-wave LDS
//         transpose (16B full-line stores).
// MODE 1: fp32 out, direct stores (64B-contiguous per 16 lanes).
// ---------------------------------------------------------------------------
template<int MODE>
__launch_bounds__(512, 2)
__global__ void gemm_mfma(const unsigned short* __restrict__ Ab,
                          const unsigned short* __restrict__ Bb,
                          const float* __restrict__ bias,
                          void* __restrict__ out0,
                          unsigned short* __restrict__ out1,
                          int M, int N, int K)
{
  constexpr int BM = 256, BN = 256, BK = 64;
  __shared__ __align__(16) unsigned short As[2][BM * BK];  // 2 x 32 KB
  __shared__ __align__(16) unsigned short Bs[2][BN * BK];  // 2 x 32 KB

  const int tid  = threadIdx.x;
  const int lane = tid & 63;
  const int w    = tid >> 6;       // 0..7
  const int wm   = w >> 2;         // 0..1  (M half)
  const int wn   = w & 3;          // 0..3  (N quarter)

  // bijective XCD swizzle: each XCD gets a contiguous chunk of tiles
  const int GX  = gridDim.x;
  const int nwg = GX * gridDim.y;           // divisible by 8 for our shapes
  int lin = blockIdx.y * GX + blockIdx.x;
  lin = (lin & 7) * (nwg >> 3) + (lin >> 3);
  const int m0 = (lin / GX) * BM;
  const int n0 = (lin % GX) * BN;
  const int NT = K / BK;

  // staging geometry: one call = 64 rows; wave w covers rows c*64+w*8 .. +7
  const int sr   = lane >> 3;                   // 0..7 row-in-slice
  const int sblk = ((lane & 7) ^ sr) * 8;       // pre-swizzled global col (elems)

  // fragment read geometry
  const int fr  = lane & 15;
  const int fb0 = (((lane >> 4) + 0) ^ (lane & 7)) * 8;   // k-step 0
  const int fb1 = (((lane >> 4) + 4) ^ (lane & 7)) * 8;   // k-step 1

  auto stage64 = [&](const unsigned short* Gp, int Kd, int grow0, int kOff,
                     unsigned short* lchunk) {
    gload16(Gp + (size_t)(grow0 + w * 8 + sr) * Kd + kOff + sblk,
            lchunk + (w * 8) * BK);
  };

  f32x4 acc[8][4] = {};

  // ---- prologue: stage tiles 0 and 1 ----
  #pragma unroll
  for (int c = 0; c < 4; ++c) stage64(Ab, K, m0 + c * 64, 0, &As[0][c * 64 * BK]);
  #pragma unroll
  for (int c = 0; c < 4; ++c) stage64(Bb, K, n0 + c * 64, 0, &Bs[0][c * 64 * BK]);
  #pragma unroll
  for (int c = 0; c < 4; ++c) stage64(Ab, K, m0 + c * 64, BK, &As[1][c * 64 * BK]);
  #pragma unroll
  for (int c = 0; c < 4; ++c) stage64(Bb, K, n0 + c * 64, BK, &Bs[1][c * 64 * BK]);
  asm volatile("s_waitcnt vmcnt(8)" ::: "memory");   // tile 0 landed
  BAR();

  for (int t = 0; t < NT; ++t) {
    const int cur = t & 1;
    const unsigned short* AL = As[cur];
    const unsigned short* BL = Bs[cur];
    const int  nxtK = (t + 2) * BK;
    const bool more = (t + 2 < NT);

    f16x8 af[4][2], bf[4][2];

    // ---- phase 0: quadrant (mq=0, nq=0) — 12 ds_reads, 16 MFMA
    #pragma unroll
    for (int i = 0; i < 4; ++i) {
      const int row = wm * 128 + i * 16 + fr;
      af[i][0] = *(const f16x8*)&AL[row * BK + fb0];
      af[i][1] = *(const f16x8*)&AL[row * BK + fb1];
    }
    #pragma unroll
    for (int j = 0; j < 2; ++j) {
      const int row = wn * 64 + j * 16 + fr;
      bf[j][0] = *(const f16x8*)&BL[row * BK + fb0];
      bf[j][1] = *(const f16x8*)&BL[row * BK + fb1];
    }
    BAR();
    __builtin_amdgcn_s_setprio(1);
    #pragma unroll
    for (int i = 0; i < 4; ++i)
      #pragma unroll
      for (int j = 0; j < 2; ++j) {
        acc[i][j] = __builtin_amdgcn_mfma_f32_16x16x32_f16(af[i][0], bf[j][0], acc[i][j], 0, 0, 0);
        acc[i][j] = __builtin_amdgcn_mfma_f32_16x16x32_f16(af[i][1], bf[j][1], acc[i][j], 0, 0, 0);
      }
    __builtin_amdgcn_s_setprio(0);
    BAR();

    // ---- phase 1: (mq=0, nq=1) — 4 ds_reads, 16 MFMA
    #pragma unroll
    for (int j = 2; j < 4; ++j) {
      const int row = wn * 64 + j * 16 + fr;
      bf[j][0] = *(const f16x8*)&BL[row * BK + fb0];
      bf[j][1] = *(const f16x8*)&BL[row * BK + fb1];
    }
    BAR();
    __builtin_amdgcn_s_setprio(1);
    #pragma unroll
    for (int i = 0; i < 4; ++i)
      #pragma unroll
      for (int j = 2; j < 4; ++j) {
        acc[i][j] = __builtin_amdgcn_mfma_f32_16x16x32_f16(af[i][0], bf[j][0], acc[i][j], 0, 0, 0);
        acc[i][j] = __builtin_amdgcn_mfma_f32_16x16x32_f16(af[i][1], bf[j][1], acc[i][j], 0, 0, 0);
      }
    __builtin_amdgcn_s_setprio(0);
    BAR();

    // ---- phase 2: (mq=1, nq=0) — 8 ds_reads; stage B chunks 0,1 and
    //      A chunks 0,2 of t+2 (their reads completed by end of phase 1)
    #pragma unroll
    for (int i = 0; i < 4; ++i) {
      const int row = wm * 128 + 64 + i * 16 + fr;
      af[i][0] = *(const f16x8*)&AL[row * BK + fb0];
      af[i][1] = *(const f16x8*)&AL[row * BK + fb1];
    }
    if (more) {
      stage64(Bb, K, n0 +   0, nxtK, &Bs[cur][0]);
      stage64(Bb, K, n0 +  64, nxtK, &Bs[cur][64 * BK]);
      stage64(Ab, K, m0 +   0, nxtK, &As[cur][0]);
      stage64(Ab, K, m0 + 128, nxtK, &As[cur][128 * BK]);
    }
    BAR();
    __builtin_amdgcn_s_setprio(1);
    #pragma unroll
    for (int i = 0; i < 4; ++i)
      #pragma unroll
      for (int j = 0; j < 2; ++j) {
        acc[4 + i][j] = __builtin_amdgcn_mfma_f32_16x16x32_f16(af[i][0], bf[j][0], acc[4 + i][j], 0, 0, 0);
        acc[4 + i][j] = __builtin_amdgcn_mfma_f32_16x16x32_f16(af[i][1], bf[j][1], acc[4 + i][j], 0, 0, 0);
      }
    __builtin_amdgcn_s_setprio(0);
    BAR();

    // ---- phase 3: (mq=1, nq=1) — 0 ds_reads; stage B chunks 2,3 + A chunks 1,3
    if (more) {
      stage64(Bb, K, n0 + 128, nxtK, &Bs[cur][128 * BK]);
      stage64(Bb, K, n0 + 192, nxtK, &Bs[cur][192 * BK]);
      stage64(Ab, K, m0 +  64, nxtK, &As[cur][64 * BK]);
      stage64(Ab, K, m0 + 192, nxtK, &As[cur][192 * BK]);
    }
    BAR();
    __builtin_amdgcn_s_setprio(1);
    #pragma unroll
    for (int i = 0; i < 4; ++i)
      #pragma unroll
      for (int j = 2; j < 4; ++j) {
        acc[4 + i][j] = __builtin_amdgcn_mfma_f32_16x16x32_f16(af[i][0], bf[j][0], acc[4 + i][j], 0, 0, 0);
        acc[4 + i][j] = __builtin_amdgcn_mfma_f32_16x16x32_f16(af[i][1], bf[j][1], acc[4 + i][j], 0, 0, 0);
      }
    __builtin_amdgcn_s_setprio(0);
    // tile t+1 ready: only the 8 staging instrs of tile t+2 may remain
    if (more) asm volatile("s_waitcnt vmcnt(8)" ::: "memory");
    else      asm volatile("s_waitcnt vmcnt(0)" ::: "memory");
    BAR();
  }

  // ---- epilogue ----
  const int col = lane & 15;
  const int rb4 = (lane >> 4) * 4;

  if (MODE == 1) {
    // fp32 direct stores: lanes 0-15 cover 64B contiguous per row
    #pragma unroll
    for (int j = 0; j < 4; ++j) {
      const int n  = n0 + wn * 64 + j * 16 + col;
      const float bv = bias[n];
      #pragma unroll
      for (int i = 0; i < 8; ++i) {
        const int mb = m0 + wm * 128 + i * 16 + rb4;
        #pragma unroll
        for (int r = 0; r < 4; ++r)
          ((float*)out0)[(size_t)(mb + r) * N + n] = acc[i][j][r] + bv;
      }
    }
  } else {
    // f16 split outputs via per-wave LDS transpose -> 16B full-line stores.
    constexpr int RS = 72;
    unsigned short* eb = (w < 4) ? ((unsigned short*)As + w * (64 * RS))
                                 : ((unsigned short*)Bs + (w - 4) * (64 * RS));
    const bool zhalf = (n0 >= IN_);   // block-uniform: n-tiles don't straddle
    float bv[4];
    #pragma unroll
    for (int j = 0; j < 4; ++j) bv[j] = bias[n0 + wn * 64 + j * 16 + col];

    const int lrow = lane >> 3;
    const int lc8  = (lane & 7) * 8;
    unsigned short* dst = zhalf ? out1 : (unsigned short*)out0;
    const int ncol0 = (zhalf ? n0 - IN_ : n0) + wn * 64 + lc8;

    #pragma unroll
    for (int h = 0; h < 2; ++h) {
      asm volatile("s_waitcnt lgkmcnt(0)" ::: "memory");  // slice reusable
      #pragma unroll
      for (int i2 = 0; i2 < 4; ++i2)
        #pragma unroll
        for (int j = 0; j < 4; ++j)
          #pragma unroll
          for (int r = 0; r < 4; ++r) {
            const float v = acc[h * 4 + i2][j][r] + bv[j];
            ((_Float16*)eb)[(i2 * 16 + rb4 + r) * RS + j * 16 + col] = (_Float16)v;
          }
      asm volatile("s_waitcnt lgkmcnt(0)" ::: "memory");
      #pragma unroll
      for (int it = 0; it < 8; ++it) {
        const int row = it * 8 + lrow;
        uint4 d = *(const uint4*)&eb[row * RS + lc8];
        if (zhalf) {
          float f[8];
          unpack_h8(d, f);
          d.x = packh2(siluf(f[0]), siluf(f[1]));
          d.y = packh2(siluf(f[2]), siluf(f[3]));
          d.z = packh2(siluf(f[4]), siluf(f[5]));
          d.w = packh2(siluf(f[6]), siluf(f[7]));
        }
        const int m = m0 + wm * 128 + h * 64 + row;
        *(uint4*)(dst + (size_t)m * IN_ + ncol0) = d;
      }
    }
  }
}

// ---------------------------------------------------------------------------
// causal depthwise conv (K=4, left pad 3) + SiLU.  f16 in/out.
// 8 channels x 4 timesteps per thread: 7 row-loads for 4 outputs.
// ---------------------------------------------------------------------------
__launch_bounds__(256)
__global__ void conv_silu_k(const uint4* __restrict__ xm,
                            const float* __restrict__ cw,   // (IN_,1,4)
                            const float* __restrict__ cb,
                            uint4* __restrict__ act)
{
  const int t = blockIdx.x * 256 + threadIdx.x;   // grid sized exactly
  const int c8 = t & 255;                         // channel group (IN_/8)
  const int s4 = (t >> 8) & (S_ / 4 - 1);         // timestep group
  const int b  = t >> 18;
  const int c  = c8 * 8;
  constexpr int RW = IN_ / 8;                     // row stride in uint4

  float w[8][4];
  #pragma unroll
  for (int j = 0; j < 8; ++j)
    *(float4*)w[j] = *(const float4*)(cw + (size_t)(c + j) * 4);
  float bias8[8];
  *(float4*)(bias8)     = *(const float4*)(cb + c);
  *(float4*)(bias8 + 4) = *(const float4*)(cb + c + 4);

  const size_t rowb = ((size_t)b * S_ + s4 * 4) * RW + c8;  // row s4*4
  float xf[7][8];
  #pragma unroll
  for (int i = 0; i < 7; ++i) {
    const int srow = s4 * 4 - 3 + i;
    if (s4 == 0 && i < 3) {
      #pragma unroll
      for (int j = 0; j < 8; ++j) xf[i][j] = 0.0f;
    } else {
      unpack_h8(xm[rowb + (long)(i - 3) * RW], xf[i]);
    }
  }

  #pragma unroll
  for (int o = 0; o < 4; ++o) {
    float r[8];
    #pragma unroll
    for (int j = 0; j < 8; ++j) r[j] = bias8[j];
    #pragma unroll
    for (int k = 0; k < 4; ++k)
      #pragma unroll
      for (int j = 0; j < 8; ++j)
        r[j] = fmaf(xf[o + k][j], w[j][k], r[j]);
    uint4 ov;
    ov.x = packh2(siluf(r[0]), siluf(r[1]));
    ov.y = packh2(siluf(r[2]), siluf(r[3]));
    ov.z = packh2(siluf(r[4]), siluf(r[5]));
    ov.w = packh2(siluf(r[6]), siluf(r[7]));
    act[rowb + (size_t)o * RW] = ov;
  }
}

// ---------------------------------------------------------------------------
// grouped 16x16 gate projections + per-chunk scan partials.
// ---------------------------------------------------------------------------
__launch_bounds__(256)
__global__ void gates_scan(const unsigned* __restrict__ actb,
                           const float* __restrict__ wf,
                           const float* __restrict__ wi,
                           const float* __restrict__ wh,
                           float2* __restrict__ part)   // [B_*IN_][NCH_]
{
  const int T  = blockIdx.x * 256 + threadIdx.x;
  const int o  = T & 15;
  const int g  = (T >> 4) & 127;
  const int ck = (T >> 11) & (NCH_ - 1);
  const int b  = T >> 18;

  h2 Wf2[8], Wi2[8], Wh2[8];
  const float* pf = wf + ((size_t)g * 16 + o) * 16;
  const float* pi = wi + ((size_t)g * 16 + o) * 16;
  const float* ph = wh + ((size_t)g * 16 + o) * 16;
  #pragma unroll
  for (int i = 0; i < 8; ++i) {
    Wf2[i] = pkrtz(pf[2 * i], pf[2 * i + 1]);
    Wi2[i] = pkrtz(pi[2 * i], pi[2 * i + 1]);
    Wh2[i] = pkrtz(ph[2 * i], ph[2 * i + 1]);
  }

  float p = 0.0f, Mx = -INFINITY, Ss = 0.0f;
  const unsigned* ap = actb + ((size_t)b * S_ + (size_t)ck * CS_) * (IN_ / 2) + g * 8;
  for (int s = 0; s < CS_; ++s) {
    union { uint4 u; h2 h[4]; } A0, A1;
    A0.u = *(const uint4*)(ap);
    A1.u = *(const uint4*)(ap + 4);
    ap += IN_ / 2;
    float fg = 0.0f, ig = 0.0f, hd = 0.0f;
    #pragma unroll
    for (int i = 0; i < 4; ++i) {
      fg = __builtin_amdgcn_fdot2(A0.h[i], Wf2[i], fg, false);
      ig = __builtin_amdgcn_fdot2(A0.h[i], Wi2[i], ig, false);
      hd = __builtin_amdgcn_fdot2(A0.h[i], Wh2[i], hd, false);
    }
    #pragma unroll
    for (int i = 0; i < 4; ++i) {
      fg = __builtin_amdgcn_fdot2(A1.h[i], Wf2[i + 4], fg, false);
      ig = __builtin_amdgcn_fdot2(A1.h[i], Wi2[i + 4], ig, false);
      hd = __builtin_amdgcn_fdot2(A1.h[i], Wh2[i + 4], hd, false);
    }
    const float diff  = spf_fast(-fg) - spf_fast(-ig);
    const float log_f = -spf_fast(diff);
    const float log_i = diff + log_f;          // sp(-d) = sp(d) - d
    const float lpos  = LN2_ * __builtin_amdgcn_logf(hd + 0.5f + EPS_);
    const float lneg  = -spf_fast(-hd) + EPS_;
    const float log_th = (hd >= 0.0f) ? lpos : lneg;
    p += log_f + EPS_;
    const float v = log_i + log_th - p;
    const float m = fmaxf(Mx, v);
    Ss = Ss * __builtin_amdgcn_exp2f((Mx - m) * LOG2E_)
       + __builtin_amdgcn_exp2f((v - m) * LOG2E_);
    Mx = m;
  }
  part[((size_t)(b * IN_ + g * 16 + o)) * NCH_ + ck] =
      make_float2(p, Mx + LN2_ * __builtin_amdgcn_logf(Ss));
}

// ---------------------------------------------------------------------------
// combine chunk partials -> h_last[b, c]
// ---------------------------------------------------------------------------
__launch_bounds__(256)
__global__ void combine_k(const float2* __restrict__ part, float* __restrict__ hlast)
{
  const int seq = blockIdx.x * 256 + threadIdx.x;
  if (seq >= B_ * IN_) return;
  const float2* pp = part + (size_t)seq * NCH_;
  float P = 0.0f, Mx = -INFINITY, Ss = 0.0f;
  for (int c = 0; c < NCH_; ++c) {
    const float2 al = pp[c];
    const float v = al.y - P;
    const float m = fmaxf(Mx, v);
    Ss = Ss * __builtin_amdgcn_exp2f((Mx - m) * LOG2E_)
       + __builtin_amdgcn_exp2f((v - m) * LOG2E_);
    Mx = m;
    P += al.x;
  }
  hlast[seq] = __builtin_amdgcn_exp2f((P + Mx) * LOG2E_) * Ss;
}

// ---------------------------------------------------------------------------
// G = (h_last + skip*act) * silu(z), written in place over the z buffer.
// ---------------------------------------------------------------------------
__launch_bounds__(256)
__global__ void gfuse_k(const unsigned* __restrict__ actb,
                        unsigned* __restrict__ zb,
                        const float* __restrict__ hlast,
                        const float* __restrict__ skipv)
{
  const size_t total  = (size_t)B_ * S_ * IN_ / 8;
  const size_t stride = (size_t)gridDim.x * blockDim.x;
  for (size_t t = (size_t)blockIdx.x * blockDim.x + threadIdx.x; t < total; t += stride) {
    const size_t e = t * 8;
    const int    c = (int)(e % IN_);
    const int    b = (int)(e / ((size_t)S_ * IN_));
    float a[8], z[8], hl[8], sk[8];
    unpack_h8(*(const uint4*)(actb + e / 2), a);
    unpack_h8(*(const uint4*)(zb   + e / 2), z);
    *(float4*)(hl)     = *(const float4*)(hlast + (size_t)b * IN_ + c);
    *(float4*)(hl + 4) = *(const float4*)(hlast + (size_t)b * IN_ + c + 4);
    *(float4*)(sk)     = *(const float4*)(skipv + c);
    *(float4*)(sk + 4) = *(const float4*)(skipv + c + 4);
    float g[8];
    #pragma unroll
    for (int j = 0; j < 8; ++j) g[j] = (hl[j] + sk[j] * a[j]) * z[j];
    uint4 o;
    o.x = packh2(g[0], g[1]);
    o.y = packh2(g[2], g[3]);
    o.z = packh2(g[4], g[5]);
    o.w = packh2(g[6], g[7]);
    *(uint4*)(zb + e / 2) = o;
  }
}

// ---------------------------------------------------------------------------
extern "C" void kernel_launch(void* const* d_in, const int* in_sizes, int n_in,
                              void* d_out, int out_size, void* d_ws, size_t ws_size,
                              hipStream_t stream)
{
  const float* x     = (const float*)d_in[0];
  const float* w_up  = (const float*)d_in[1];
  const float* b_up  = (const float*)d_in[2];
  const float* cw    = (const float*)d_in[3];
  const float* cb    = (const float*)d_in[4];
  const float* skipv = (const float*)d_in[5];
  const float* w_f   = (const float*)d_in[6];
  const float* w_i   = (const float*)d_in[7];
  const float* w_h   = (const float*)d_in[8];
  const float* w_dn  = (const float*)d_in[9];
  const float* b_dn  = (const float*)d_in[10];
  float* out = (float*)d_out;

  // workspace layout with lifetime-based aliasing (max ~210 MB):
  //  [0,   67M): xminb (dead after conv) -> then wdb @0 (4MB),
  //              part @8.39M (8.39MB), hlast @16.78M (32KB)
  //  [67M, 134M): zb (silu(z) -> G in place via gfuse)
  //  [134M,201M): actb;  xb (f16 x, 33.5M) aliases this region (dead pre-conv)
  //  [201M,210M): wub (8.4MB)
  char* ws = (char*)d_ws;
  unsigned short* xminb = (unsigned short*)(ws);
  unsigned short* wdb   = (unsigned short*)(ws);                    // after conv
  float2*         part  = (float2*)(ws + 8388608ULL);               // after conv
  float*          hlast = (float*)(ws + 16777216ULL);               // after conv
  unsigned short* zb    = (unsigned short*)(ws + 67108864ULL);
  unsigned short* actb  = (unsigned short*)(ws + 134217728ULL);
  unsigned short* xb    = (unsigned short*)(ws + 134217728ULL);     // pre-conv alias
  unsigned short* wub   = (unsigned short*)(ws + 201326592ULL);

  const int M = B_ * S_;   // 16384

  // 0) fp32 -> f16 conversions for MFMA operands
  cvt_f16<<<2048, 256, 0, stream>>>(x,    (unsigned*)xb,  (long)M * D_ / 8);
  cvt_f16<<<512,  256, 0, stream>>>(w_up, (unsigned*)wub, (long)2 * IN_ * D_ / 8);

  // 1) proj-up: xb @ wub^T + b_up -> xmin(f16) | silu(z)(f16)
  gemm_mfma<0><<<dim3((2 * IN_) / 256, M / 256), 512, 0, stream>>>(
      xb, wub, b_up, xminb, (unsigned short*)zb, M, 2 * IN_, D_);

  // 2) causal depthwise conv + SiLU -> act(f16)  (4 steps x 8 ch / thread)
  conv_silu_k<<<(B_ * (S_ / 4) * (IN_ / 8)) / 256, 256, 0, stream>>>(
      (const uint4*)xminb, cw, cb, (uint4*)actb);

  // 2b) w_down -> f16 (into region freed by xminb)
  cvt_f16<<<256, 256, 0, stream>>>(w_dn, (unsigned*)wdb, (long)D_ * IN_ / 8);

  // 3) grouped gate projections + chunked scan partials
  gates_scan<<<(B_ * 128 * 16 * NCH_) / 256, 256, 0, stream>>>(
      (const unsigned*)actb, w_f, w_i, w_h, part);

  // 4) combine partials -> h_last
  combine_k<<<(B_ * IN_ + 255) / 256, 256, 0, stream>>>(part, hlast);

  // 5) G = (h_last + skip*act) * silu(z), in place over zb
  gfuse_k<<<2048, 256, 0, stream>>>((const unsigned*)actb, (unsigned*)zb, hlast, skipv);

  // 6) proj-down: G(f16) @ wdb^T + b_dn -> out (fp32)
  gemm_mfma<1><<<dim3(D_ / 256, M / 256), 512, 0, stream>>>(
      zb, wdb, b_dn, out, nullptr, M, D_, IN_);
}

// Round 10
// 398.050 us; speedup vs baseline: 1.3991x; 1.0291x over previous
//
#include <hip/hip_runtime.h>
#include <math.h>

// ---- problem constants (from reference) ----
constexpr int B_  = 4;
constexpr int S_  = 4096;
constexpr int D_  = 1024;   // DIM
constexpr int IN_ = 2048;   // INNER
constexpr float EPS_ = 1e-8f;
constexpr int NCH_ = 128;         // chunks per sequence for the scan
constexpr int CS_  = S_ / NCH_;   // 32 timesteps per chunk
constexpr float LOG2E_ = 1.4426950408889634f;
constexpr float LN2_   = 0.6931471805599453f;
constexpr float EPS2_  = 1.4426950408889634e-8f;   // EPS * log2(e)

typedef __attribute__((ext_vector_type(8))) _Float16 f16x8;
typedef __attribute__((ext_vector_type(2))) _Float16 h2;
typedef __attribute__((ext_vector_type(4))) float    f32x4;

#define BAR() asm volatile("s_barrier" ::: "memory")

// ---- helpers ----
__device__ __forceinline__ h2 pkrtz(float a, float b) {
  auto r = __builtin_amdgcn_cvt_pkrtz(a, b);
  union { decltype(r) r_; h2 h; } c; c.r_ = r; return c.h;
}
__device__ __forceinline__ unsigned packh2(float a, float b) {
  auto r = __builtin_amdgcn_cvt_pkrtz(a, b);
  union { decltype(r) r_; unsigned u; } c; c.r_ = r; return c.u;
}
__device__ __forceinline__ void unpack_h8(uint4 v, float* f) {
  union { uint4 u; _Float16 h[8]; } c; c.u = v;
  #pragma unroll
  for (int i = 0; i < 8; ++i) f[i] = (float)c.h[i];
}
// base-2 softplus: sp2(t) = max(t,0) + log2(1 + 2^-|t|);  softplus(x) = LN2*sp2(x*LOG2E)
__device__ __forceinline__ float sp2(float t) {
  const float e = __builtin_amdgcn_exp2f(-fabsf(t));
  return fmaxf(t, 0.0f) + __builtin_amdgcn_logf(1.0f + e);
}
__device__ __forceinline__ float siluf(float x) {
  return x * __builtin_amdgcn_rcpf(1.0f + __builtin_amdgcn_exp2f(-x * LOG2E_));
}

// async global->LDS, 16 B per lane (wave-uniform LDS base + lane*16)
__device__ __forceinline__ void gload16(const void* g, void* l) {
  __builtin_amdgcn_global_load_lds(
      (const __attribute__((address_space(1))) void*)g,
      (__attribute__((address_space(3))) void*)l,
      16, 0, 0);
}

// ---------------------------------------------------------------------------
// fp32 -> f16 conversion for two buffers in one launch (8 elems/thread)
// ---------------------------------------------------------------------------
__launch_bounds__(256)
__global__ void cvt_f16_2(const float* __restrict__ in0, unsigned* __restrict__ out0,
                          long n8_0,
                          const float* __restrict__ in1, unsigned* __restrict__ out1,
                          long n8_1)
{
  const long total  = n8_0 + n8_1;
  const long stride = (long)gridDim.x * blockDim.x;
  for (long t = (long)blockIdx.x * blockDim.x + threadIdx.x; t < total; t += stride) {
    const float* in  = (t < n8_0) ? in0  : in1;
    unsigned*    out = (t < n8_0) ? out0 : out1;
    const long   i   = (t < n8_0) ? t    : t - n8_0;
    const float4 a = *(const float4*)(in + i * 8);
    const float4 b = *(const float4*)(in + i * 8 + 4);
    uint4 o;
    o.x = packh2(a.x, a.y);
    o.y = packh2(a.z, a.w);
    o.z = packh2(b.x, b.y);
    o.w = packh2(b.z, b.w);
    *(uint4*)(out + i * 4) = o;
  }
}

__launch_bounds__(256)
__global__ void cvt_f16(const float* __restrict__ in, unsigned* __restrict__ outp,
                        long n8)
{
  const long stride = (long)gridDim.x * blockDim.x;
  for (long i = (long)blockIdx.x * blockDim.x + threadIdx.x; i < n8; i += stride) {
    const float4 a = *(const float4*)(in + i * 8);
    const float4 b = *(const float4*)(in + i * 8 + 4);
    uint4 o;
    o.x = packh2(a.x, a.y);
    o.y = packh2(a.z, a.w);
    o.z = packh2(b.x, b.y);
    o.w = packh2(b.z, b.w);
    *(uint4*)(outp + i * 4) = o;
  }
}

// ---------------------------------------------------------------------------
// f16 MFMA NT GEMM, 4-phase schedule, 256x256 tile, BK=64, 8 waves (2Mx4N),
// double-buffered LDS (128 KiB), XOR-16B-block swizzle, counted vmcnt(8),
// setprio, bijective XCD swizzle, staging spread 2-2-4 across phases 1/2/3.
// MODE 0: split epilogue -> xmin(f16) | silu(z)(f16) via per-wave LDS
//         transpose (16B full-line stores).
// MODE 1: fp32 out, direct stores (64B-contiguous per 16 lanes).
// ---------------------------------------------------------------------------
template<int MODE>
__launch_bounds__(512, 2)
__global__ void gemm_mfma(const unsigned short* __restrict__ Ab,
                          const unsigned short* __restrict__ Bb,
                          const float* __restrict__ bias,
                          void* __restrict__ out0,
                          unsigned short* __restrict__ out1,
                          int M, int N, int K)
{
  constexpr int BM = 256, BN = 256, BK = 64;
  __shared__ __align__(16) unsigned short As[2][BM * BK];  // 2 x 32 KB
  __shared__ __align__(16) unsigned short Bs[2][BN * BK];  // 2 x 32 KB

  const int tid  = threadIdx.x;
  const int lane = tid & 63;
  const int w    = tid >> 6;       // 0..7
  const int wm   = w >> 2;         // 0..1  (M half)
  const int wn   = w & 3;          // 0..3  (N quarter)

  // bijective XCD swizzle
  const int GX  = gridDim.x;
  const int nwg = GX * gridDim.y;           // divisible by 8 for our shapes
  int lin = blockIdx.y * GX + blockIdx.x;
  lin = (lin & 7) * (nwg >> 3) + (lin >> 3);
  const int m0 = (lin / GX) * BM;
  const int n0 = (lin % GX) * BN;
  const int NT = K / BK;

  // staging geometry
  const int sr   = lane >> 3;                   // 0..7 row-in-slice
  const int sblk = ((lane & 7) ^ sr) * 8;       // pre-swizzled global col

  // fragment read geometry
  const int fr  = lane & 15;
  const int fb0 = (((lane >> 4) + 0) ^ (lane & 7)) * 8;
  const int fb1 = (((lane >> 4) + 4) ^ (lane & 7)) * 8;

  auto stage64 = [&](const unsigned short* Gp, int Kd, int grow0, int kOff,
                     unsigned short* lchunk) {
    gload16(Gp + (size_t)(grow0 + w * 8 + sr) * Kd + kOff + sblk,
            lchunk + (w * 8) * BK);
  };

  f32x4 acc[8][4] = {};

  // ---- prologue: stage tiles 0 and 1 ----
  #pragma unroll
  for (int c = 0; c < 4; ++c) stage64(Ab, K, m0 + c * 64, 0, &As[0][c * 64 * BK]);
  #pragma unroll
  for (int c = 0; c < 4; ++c) stage64(Bb, K, n0 + c * 64, 0, &Bs[0][c * 64 * BK]);
  #pragma unroll
  for (int c = 0; c < 4; ++c) stage64(Ab, K, m0 + c * 64, BK, &As[1][c * 64 * BK]);
  #pragma unroll
  for (int c = 0; c < 4; ++c) stage64(Bb, K, n0 + c * 64, BK, &Bs[1][c * 64 * BK]);
  asm volatile("s_waitcnt vmcnt(8)" ::: "memory");   // tile 0 landed
  BAR();

  for (int t = 0; t < NT; ++t) {
    const int cur = t & 1;
    const unsigned short* AL = As[cur];
    const unsigned short* BL = Bs[cur];
    const int  nxtK = (t + 2) * BK;
    const bool more = (t + 2 < NT);

    f16x8 af[4][2], bf[4][2];

    // ---- phase 0: quadrant (mq=0, nq=0) — 12 ds_reads, 16 MFMA
    #pragma unroll
    for (int i = 0; i < 4; ++i) {
      const int row = wm * 128 + i * 16 + fr;
      af[i][0] = *(const f16x8*)&AL[row * BK + fb0];
      af[i][1] = *(const f16x8*)&AL[row * BK + fb1];
    }
    #pragma unroll
    for (int j = 0; j < 2; ++j) {
      const int row = wn * 64 + j * 16 + fr;
      bf[j][0] = *(const f16x8*)&BL[row * BK + fb0];
      bf[j][1] = *(const f16x8*)&BL[row * BK + fb1];
    }
    BAR();
    __builtin_amdgcn_s_setprio(1);
    #pragma unroll
    for (int i = 0; i < 4; ++i)
      #pragma unroll
      for (int j = 0; j < 2; ++j) {
        acc[i][j] = __builtin_amdgcn_mfma_f32_16x16x32_f16(af[i][0], bf[j][0], acc[i][j], 0, 0, 0);
        acc[i][j] = __builtin_amdgcn_mfma_f32_16x16x32_f16(af[i][1], bf[j][1], acc[i][j], 0, 0, 0);
      }
    __builtin_amdgcn_s_setprio(0);
    BAR();

    // ---- phase 1: (mq=0, nq=1) — 4 ds_reads; stage A chunks 0,2 of t+2
    //      (A{0,2} fully consumed by end of phase 0 + barrier)
    #pragma unroll
    for (int j = 2; j < 4; ++j) {
      const int row = wn * 64 + j * 16 + fr;
      bf[j][0] = *(const f16x8*)&BL[row * BK + fb0];
      bf[j][1] = *(const f16x8*)&BL[row * BK + fb1];
    }
    if (more) {
      stage64(Ab, K, m0 +   0, nxtK, &As[cur][0]);
      stage64(Ab, K, m0 + 128, nxtK, &As[cur][128 * BK]);
    }
    BAR();
    __builtin_amdgcn_s_setprio(1);
    #pragma unroll
    for (int i = 0; i < 4; ++i)
      #pragma unroll
      for (int j = 2; j < 4; ++j) {
        acc[i][j] = __builtin_amdgcn_mfma_f32_16x16x32_f16(af[i][0], bf[j][0], acc[i][j], 0, 0, 0);
        acc[i][j] = __builtin_amdgcn_mfma_f32_16x16x32_f16(af[i][1], bf[j][1], acc[i][j], 0, 0, 0);
      }
    __builtin_amdgcn_s_setprio(0);
    BAR();

    // ---- phase 2: (mq=1, nq=0) — 8 ds_reads; stage B chunks 0,1 of t+2
    //      (all B consumed by end of phase 1 + barrier)
    #pragma unroll
    for (int i = 0; i < 4; ++i) {
      const int row = wm * 128 + 64 + i * 16 + fr;
      af[i][0] = *(const f16x8*)&AL[row * BK + fb0];
      af[i][1] = *(const f16x8*)&AL[row * BK + fb1];
    }
    if (more) {
      stage64(Bb, K, n0 +   0, nxtK, &Bs[cur][0]);
      stage64(Bb, K, n0 +  64, nxtK, &Bs[cur][64 * BK]);
    }
    BAR();
    __builtin_amdgcn_s_setprio(1);
    #pragma unroll
    for (int i = 0; i < 4; ++i)
      #pragma unroll
      for (int j = 0; j < 2; ++j) {
        acc[4 + i][j] = __builtin_amdgcn_mfma_f32_16x16x32_f16(af[i][0], bf[j][0], acc[4 + i][j], 0, 0, 0);
        acc[4 + i][j] = __builtin_amdgcn_mfma_f32_16x16x32_f16(af[i][1], bf[j][1], acc[4 + i][j], 0, 0, 0);
      }
    __builtin_amdgcn_s_setprio(0);
    BAR();

    // ---- phase 3: (mq=1, nq=1) — 0 ds_reads; stage A chunks 1,3 + B chunks 2,3
    if (more) {
      stage64(Ab, K, m0 +  64, nxtK, &As[cur][64 * BK]);
      stage64(Ab, K, m0 + 192, nxtK, &As[cur][192 * BK]);
      stage64(Bb, K, n0 + 128, nxtK, &Bs[cur][128 * BK]);
      stage64(Bb, K, n0 + 192, nxtK, &Bs[cur][192 * BK]);
    }
    BAR();
    __builtin_amdgcn_s_setprio(1);
    #pragma unroll
    for (int i = 0; i < 4; ++i)
      #pragma unroll
      for (int j = 2; j < 4; ++j) {
        acc[4 + i][j] = __builtin_amdgcn_mfma_f32_16x16x32_f16(af[i][0], bf[j][0], acc[4 + i][j], 0, 0, 0);
        acc[4 + i][j] = __builtin_amdgcn_mfma_f32_16x16x32_f16(af[i][1], bf[j][1], acc[4 + i][j], 0, 0, 0);
      }
    __builtin_amdgcn_s_setprio(0);
    // tile t+1 ready: only the 8 staging instrs of tile t+2 may remain
    if (more) asm volatile("s_waitcnt vmcnt(8)" ::: "memory");
    else      asm volatile("s_waitcnt vmcnt(0)" ::: "memory");
    BAR();
  }

  // ---- epilogue ----
  const int col = lane & 15;
  const int rb4 = (lane >> 4) * 4;

  if (MODE == 1) {
    #pragma unroll
    for (int j = 0; j < 4; ++j) {
      const int n  = n0 + wn * 64 + j * 16 + col;
      const float bv = bias[n];
      #pragma unroll
      for (int i = 0; i < 8; ++i) {
        const int mb = m0 + wm * 128 + i * 16 + rb4;
        #pragma unroll
        for (int r = 0; r < 4; ++r)
          ((float*)out0)[(size_t)(mb + r) * N + n] = acc[i][j][r] + bv;
      }
    }
  } else {
    // f16 split outputs via per-wave LDS transpose -> 16B full-line stores.
    constexpr int RS = 72;
    unsigned short* eb = (w < 4) ? ((unsigned short*)As + w * (64 * RS))
                                 : ((unsigned short*)Bs + (w - 4) * (64 * RS));
    const bool zhalf = (n0 >= IN_);   // block-uniform
    float bv[4];
    #pragma unroll
    for (int j = 0; j < 4; ++j) bv[j] = bias[n0 + wn * 64 + j * 16 + col];

    const int lrow = lane >> 3;
    const int lc8  = (lane & 7) * 8;
    unsigned short* dst = zhalf ? out1 : (unsigned short*)out0;
    const int ncol0 = (zhalf ? n0 - IN_ : n0) + wn * 64 + lc8;

    #pragma unroll
    for (int h = 0; h < 2; ++h) {
      asm volatile("s_waitcnt lgkmcnt(0)" ::: "memory");
      #pragma unroll
      for (int i2 = 0; i2 < 4; ++i2)
        #pragma unroll
        for (int j = 0; j < 4; ++j)
          #pragma unroll
          for (int r = 0; r < 4; ++r) {
            const float v = acc[h * 4 + i2][j][r] + bv[j];
            ((_Float16*)eb)[(i2 * 16 + rb4 + r) * RS + j * 16 + col] = (_Float16)v;
          }
      asm volatile("s_waitcnt lgkmcnt(0)" ::: "memory");
      #pragma unroll
      for (int it = 0; it < 8; ++it) {
        const int row = it * 8 + lrow;
        uint4 d = *(const uint4*)&eb[row * RS + lc8];
        if (zhalf) {
          float f[8];
          unpack_h8(d, f);
          d.x = packh2(siluf(f[0]), siluf(f[1]));
          d.y = packh2(siluf(f[2]), siluf(f[3]));
          d.z = packh2(siluf(f[4]), siluf(f[5]));
          d.w = packh2(siluf(f[6]), siluf(f[7]));
        }
        const int m = m0 + wm * 128 + h * 64 + row;
        *(uint4*)(dst + (size_t)m * IN_ + ncol0) = d;
      }
    }
  }
}

// ---------------------------------------------------------------------------
// causal depthwise conv (K=4, left pad 3) + SiLU.  f16 in/out.
// 8 channels x 4 timesteps per thread: 7 row-loads for 4 outputs.
// ---------------------------------------------------------------------------
__launch_bounds__(256)
__global__ void conv_silu_k(const uint4* __restrict__ xm,
                            const float* __restrict__ cw,   // (IN_,1,4)
                            const float* __restrict__ cb,
                            uint4* __restrict__ act)
{
  const int t = blockIdx.x * 256 + threadIdx.x;   // grid sized exactly
  const int c8 = t & 255;                         // channel group (IN_/8)
  const int s4 = (t >> 8) & (S_ / 4 - 1);         // timestep group
  const int b  = t >> 18;
  const int c  = c8 * 8;
  constexpr int RW = IN_ / 8;                     // row stride in uint4

  float w[8][4];
  #pragma unroll
  for (int j = 0; j < 8; ++j)
    *(float4*)w[j] = *(const float4*)(cw + (size_t)(c + j) * 4);
  float bias8[8];
  *(float4*)(bias8)     = *(const float4*)(cb + c);
  *(float4*)(bias8 + 4) = *(const float4*)(cb + c + 4);

  const size_t rowb = ((size_t)b * S_ + s4 * 4) * RW + c8;  // row s4*4
  float xf[7][8];
  #pragma unroll
  for (int i = 0; i < 7; ++i) {
    if (s4 == 0 && i < 3) {
      #pragma unroll
      for (int j = 0; j < 8; ++j) xf[i][j] = 0.0f;
    } else {
      unpack_h8(xm[rowb + (long)(i - 3) * RW], xf[i]);
    }
  }

  #pragma unroll
  for (int o = 0; o < 4; ++o) {
    float r[8];
    #pragma unroll
    for (int j = 0; j < 8; ++j) r[j] = bias8[j];
    #pragma unroll
    for (int k = 0; k < 4; ++k)
      #pragma unroll
      for (int j = 0; j < 8; ++j)
        r[j] = fmaf(xf[o + k][j], w[j][k], r[j]);
    uint4 ov;
    ov.x = packh2(siluf(r[0]), siluf(r[1]));
    ov.y = packh2(siluf(r[2]), siluf(r[3]));
    ov.z = packh2(siluf(r[4]), siluf(r[5]));
    ov.w = packh2(siluf(r[6]), siluf(r[7]));
    act[rowb + (size_t)o * RW] = ov;
  }
}

// ---------------------------------------------------------------------------
// grouped 16x16 gate projections + per-chunk scan partials, base-2 log domain.
// W_f/W_i premultiplied by log2(e) so fdot2 emits base-2 gates directly.
// ---------------------------------------------------------------------------
__launch_bounds__(256)
__global__ void gates_scan(const unsigned* __restrict__ actb,
                           const float* __restrict__ wf,
                           const float* __restrict__ wi,
                           const float* __restrict__ wh,
                           float2* __restrict__ part)   // [B_*IN_][NCH_]
{
  const int T  = blockIdx.x * 256 + threadIdx.x;
  const int o  = T & 15;
  const int g  = (T >> 4) & 127;
  const int ck = (T >> 11) & (NCH_ - 1);
  const int b  = T >> 18;

  h2 Wf2[8], Wi2[8], Wh2[8];
  const float* pf = wf + ((size_t)g * 16 + o) * 16;
  const float* pi = wi + ((size_t)g * 16 + o) * 16;
  const float* ph = wh + ((size_t)g * 16 + o) * 16;
  #pragma unroll
  for (int i = 0; i < 8; ++i) {
    Wf2[i] = pkrtz(pf[2 * i] * LOG2E_, pf[2 * i + 1] * LOG2E_);
    Wi2[i] = pkrtz(pi[2 * i] * LOG2E_, pi[2 * i + 1] * LOG2E_);
    Wh2[i] = pkrtz(ph[2 * i], ph[2 * i + 1]);
  }

  float p = 0.0f, Mx = -INFINITY, Ss = 0.0f;
  const unsigned* ap = actb + ((size_t)b * S_ + (size_t)ck * CS_) * (IN_ / 2) + g * 8;
  for (int s = 0; s < CS_; ++s) {
    union { uint4 u; h2 h[4]; } A0, A1;
    A0.u = *(const uint4*)(ap);
    A1.u = *(const uint4*)(ap + 4);
    ap += IN_ / 2;
    float fg = 0.0f, ig = 0.0f, hd = 0.0f;   // fg, ig already in base-2 units
    #pragma unroll
    for (int i = 0; i < 4; ++i) {
      fg = __builtin_amdgcn_fdot2(A0.h[i], Wf2[i], fg, false);
      ig = __builtin_amdgcn_fdot2(A0.h[i], Wi2[i], ig, false);
      hd = __builtin_amdgcn_fdot2(A0.h[i], Wh2[i], hd, false);
    }
    #pragma unroll
    for (int i = 0; i < 4; ++i) {
      fg = __builtin_amdgcn_fdot2(A1.h[i], Wf2[i + 4], fg, false);
      ig = __builtin_amdgcn_fdot2(A1.h[i], Wi2[i + 4], ig, false);
      hd = __builtin_amdgcn_fdot2(A1.h[i], Wh2[i + 4], hd, false);
    }
    // all log-quantities below are in base-2 units
    const float diff  = sp2(-fg) - sp2(-ig);
    const float log_f = -sp2(diff);
    const float log_i = diff + log_f;          // sp2(-d) = sp2(d) - d
    const float lpos  = __builtin_amdgcn_logf(hd + 0.5f + EPS_);
    const float lneg  = -sp2(-hd * LOG2E_) + EPS2_;
    const float log_th = (hd >= 0.0f) ? lpos : lneg;
    p += log_f + EPS2_;
    const float v = log_i + log_th - p;
    const float m = fmaxf(Mx, v);
    Ss = Ss * __builtin_amdgcn_exp2f(Mx - m) + __builtin_amdgcn_exp2f(v - m);
    Mx = m;
  }
  part[((size_t)(b * IN_ + g * 16 + o)) * NCH_ + ck] =
      make_float2(p, Mx + __builtin_amdgcn_logf(Ss));
}

// ---------------------------------------------------------------------------
// combine chunk partials -> h_last[b, c]   (base-2 domain throughout)
// ---------------------------------------------------------------------------
__launch_bounds__(256)
__global__ void combine_k(const float2* __restrict__ part, float* __restrict__ hlast)
{
  const int seq = blockIdx.x * 256 + threadIdx.x;
  if (seq >= B_ * IN_) return;
  const float2* pp = part + (size_t)seq * NCH_;
  float P = 0.0f, Mx = -INFINITY, Ss = 0.0f;
  for (int c = 0; c < NCH_; ++c) {
    const float2 al = pp[c];
    const float v = al.y - P;
    const float m = fmaxf(Mx, v);
    Ss = Ss * __builtin_amdgcn_exp2f(Mx - m) + __builtin_amdgcn_exp2f(v - m);
    Mx = m;
    P += al.x;
  }
  hlast[seq] = __builtin_amdgcn_exp2f(P + Mx) * Ss;
}

// ---------------------------------------------------------------------------
// G = (h_last + skip*act) * silu(z), written in place over the z buffer.
// ---------------------------------------------------------------------------
__launch_bounds__(256)
__global__ void gfuse_k(const unsigned* __restrict__ actb,
                        unsigned* __restrict__ zb,
                        const float* __restrict__ hlast,
                        const float* __restrict__ skipv)
{
  const size_t total  = (size_t)B_ * S_ * IN_ / 8;
  const size_t stride = (size_t)gridDim.x * blockDim.x;
  for (size_t t = (size_t)blockIdx.x * blockDim.x + threadIdx.x; t < total; t += stride) {
    const size_t e = t * 8;
    const int    c = (int)(e % IN_);
    const int    b = (int)(e / ((size_t)S_ * IN_));
    float a[8], z[8], hl[8], sk[8];
    unpack_h8(*(const uint4*)(actb + e / 2), a);
    unpack_h8(*(const uint4*)(zb   + e / 2), z);
    *(float4*)(hl)     = *(const float4*)(hlast + (size_t)b * IN_ + c);
    *(float4*)(hl + 4) = *(const float4*)(hlast + (size_t)b * IN_ + c + 4);
    *(float4*)(sk)     = *(const float4*)(skipv + c);
    *(float4*)(sk + 4) = *(const float4*)(skipv + c + 4);
    float g[8];
    #pragma unroll
    for (int j = 0; j < 8; ++j) g[j] = (hl[j] + sk[j] * a[j]) * z[j];
    uint4 o;
    o.x = packh2(g[0], g[1]);
    o.y = packh2(g[2], g[3]);
    o.z = packh2(g[4], g[5]);
    o.w = packh2(g[6], g[7]);
    *(uint4*)(zb + e / 2) = o;
  }
}

// ---------------------------------------------------------------------------
extern "C" void kernel_launch(void* const* d_in, const int* in_sizes, int n_in,
                              void* d_out, int out_size, void* d_ws, size_t ws_size,
                              hipStream_t stream)
{
  const float* x     = (const float*)d_in[0];
  const float* w_up  = (const float*)d_in[1];
  const float* b_up  = (const float*)d_in[2];
  const float* cw    = (const float*)d_in[3];
  const float* cb    = (const float*)d_in[4];
  const float* skipv = (const float*)d_in[5];
  const float* w_f   = (const float*)d_in[6];
  const float* w_i   = (const float*)d_in[7];
  const float* w_h   = (const float*)d_in[8];
  const float* w_dn  = (const float*)d_in[9];
  const float* b_dn  = (const float*)d_in[10];
  float* out = (float*)d_out;

  // workspace layout with lifetime-based aliasing (max ~210 MB):
  //  [0,   67M): xminb (dead after conv) -> then wdb @0 (4MB),
  //              part @8.39M (8.39MB), hlast @16.78M (32KB)
  //  [67M, 134M): zb (silu(z) -> G in place via gfuse)
  //  [134M,201M): actb;  xb (f16 x, 33.5M) aliases this region (dead pre-conv)
  //  [201M,210M): wub (8.4MB)
  char* ws = (char*)d_ws;
  unsigned short* xminb = (unsigned short*)(ws);
  unsigned short* wdb   = (unsigned short*)(ws);                    // after conv
  float2*         part  = (float2*)(ws + 8388608ULL);               // after conv
  float*          hlast = (float*)(ws + 16777216ULL);               // after conv
  unsigned short* zb    = (unsigned short*)(ws + 67108864ULL);
  unsigned short* actb  = (unsigned short*)(ws + 134217728ULL);
  unsigned short* xb    = (unsigned short*)(ws + 134217728ULL);     // pre-conv alias
  unsigned short* wub   = (unsigned short*)(ws + 201326592ULL);

  const int M = B_ * S_;   // 16384

  // 0) fp32 -> f16 conversions for MFMA operands (single launch)
  cvt_f16_2<<<2560, 256, 0, stream>>>(
      x,    (unsigned*)xb,  (long)M * D_ / 8,
      w_up, (unsigned*)wub, (long)2 * IN_ * D_ / 8);

  // 1) proj-up: xb @ wub^T + b_up -> xmin(f16) | silu(z)(f16)
  gemm_mfma<0><<<dim3((2 * IN_) / 256, M / 256), 512, 0, stream>>>(
      xb, wub, b_up, xminb, (unsigned short*)zb, M, 2 * IN_, D_);

  // 2) causal depthwise conv + SiLU -> act(f16)  (4 steps x 8 ch / thread)
  conv_silu_k<<<(B_ * (S_ / 4) * (IN_ / 8)) / 256, 256, 0, stream>>>(
      (const uint4*)xminb, cw, cb, (uint4*)actb);

  // 2b) w_down -> f16 (into region freed by xminb)
  cvt_f16<<<256, 256, 0, stream>>>(w_dn, (unsigned*)wdb, (long)D_ * IN_ / 8);

  // 3) grouped gate projections + chunked scan partials
  gates_scan<<<(B_ * 128 * 16 * NCH_) / 256, 256, 0, stream>>>(
      (const unsigned*)actb, w_f, w_i, w_h, part);

  // 4) combine partials -> h_last
  combine_k<<<(B_ * IN_ + 255) / 256, 256, 0, stream>>>(part, hlast);

  // 5) G = (h_last + skip*act) * silu(z), in place over zb
  gfuse_k<<<2048, 256, 0, stream>>>((const unsigned*)actb, (unsigned*)zb, hlast, skipv);

  // 6) proj-down: G(f16) @ wdb^T + b_dn -> out (fp32)
  gemm_mfma<1><<<dim3(D_ / 256, M / 256), 512, 0, stream>>>(
      zb, wdb, b_dn, out, nullptr, M, D_, IN_);
}